// Round 12
// baseline (209.076 us; speedup 1.0000x reference)
//
#include <hip/hip_runtime.h>
#include <hip/hip_bf16.h>
#include <stdint.h>

#define NR 384          // total rows
#define DD 73728        // C*H*W
#define PDV 16          // N_PARTS * N_DATASETS
#define BSV 192         // batch size
#define KSPLIT 96       // split-K factor
#define KCH 768         // DD / KSPLIT
#define BK 32           // K-step per iteration
#define NIT 24          // KCH / BK
#define RS 40           // LDS row stride bf16 (80 B = 20 banks, 16B-aligned)
#define NTILE 21        // 6*7/2 symmetric 64x64 tiles

typedef __bf16 bf16;
typedef __attribute__((ext_vector_type(4))) __bf16 bf16x4;
typedef __attribute__((ext_vector_type(8))) __bf16 bf16x8;
typedef __attribute__((ext_vector_type(4))) float f32x4;

// ---------------------------------------------------------------- kernel 1
// Fused demean + cast + partial Gram — ONE WAVE PER BLOCK, ZERO barriers.
// R11 post-mortem: block-level barrier lockstep serializes VMEM/LDS/MFMA
// phases and makes HBM/L2 traffic bursty (~2.5 TB/s observed). Here each
// 64-lane wave owns a 64x64 tile: all LDS traffic is same-wave (DS ops are
// in-order per wave, no sync needed), depth-2 register pipeline keeps ~17
// loads in flight, and 8 independent waves/CU stream VMEM continuously.
__global__ __launch_bounds__(64, 2) void k_gram(const float* __restrict__ X,
                                                const float* __restrict__ M,
                                                float* __restrict__ Gp) {
    __shared__ bf16 ash[64 * RS];      // 5 KB
    __shared__ bf16 bsh[64 * RS];      // 5 KB  (8 blocks/CU -> 80 KB)
    const int lane = threadIdx.x;      // 0..63 (one wave)
    const int quad = lane >> 4;
    const int l15  = lane & 15;
    const int srow = lane >> 3;        // 0..7 staging row base
    const int fseg = lane & 7;         // 16B segment within 128B row
    const int s2   = srow >> 2;        // 0/1: dataset id parity base

    int xcd  = blockIdx.x & 7;
    int g    = blockIdx.x >> 3;
    int tile = g % NTILE;
    int ks   = xcd + 8 * (g / NTILE);  // 21 tiles of one ks share an XCD

    int tp = 0, rem = tile;            // tile -> (tp,tq), tp<=tq, 64-panels
    while (rem >= 6 - tp) { rem -= 6 - tp; ++tp; }
    int tq = tp + rem;
    const bool diag = (tp == tq);

    const float* Xa = X + (size_t)(tp * 64) * DD;
    const float* Xb = X + (size_t)(tq * 64) * DD;
    // dataset id of row 8p+srow = (2p + s2) & 3: even p -> s2, odd p -> s2+2
    const float* Me = M + (size_t)s2 * DD;
    const float* Mo = M + (size_t)(s2 + 2) * DD;
    const size_t k0 = (size_t)ks * KCH;

    f32x4 acc[4][4];
#pragma unroll
    for (int i = 0; i < 4; ++i)
#pragma unroll
        for (int j = 0; j < 4; ++j) acc[i][j] = (f32x4){0.f, 0.f, 0.f, 0.f};

    float4 xa0[8], xb0[8], xa1[8], xb1[8];   // depth-2 register pipeline
    float4 me0, mo0, me1, mo1;

    auto load_it = [&](int it, float4 (&xa)[8], float4 (&xb)[8],
                       float4& me, float4& mo) {
        size_t gk = k0 + (size_t)it * BK + fseg * 4;
        me = *(const float4*)(Me + gk);
        mo = *(const float4*)(Mo + gk);
#pragma unroll
        for (int p = 0; p < 8; ++p)
            xa[p] = *(const float4*)(Xa + (size_t)(8 * p + srow) * DD + gk);
        if (!diag)
#pragma unroll
            for (int p = 0; p < 8; ++p)
                xb[p] = *(const float4*)(Xb + (size_t)(8 * p + srow) * DD + gk);
    };
    auto stage_it = [&](float4 (&xa)[8], float4 (&xb)[8],
                        float4& me, float4& mo) {
#pragma unroll
        for (int p = 0; p < 8; ++p) {
            float4 m4 = (p & 1) ? mo : me;
            int row = 8 * p + srow;
            bf16x4 za;
            za[0] = (bf16)(xa[p].x - m4.x); za[1] = (bf16)(xa[p].y - m4.y);
            za[2] = (bf16)(xa[p].z - m4.z); za[3] = (bf16)(xa[p].w - m4.w);
            *(bf16x4*)&ash[row * RS + fseg * 4] = za;
            if (!diag) {
                bf16x4 zb;
                zb[0] = (bf16)(xb[p].x - m4.x); zb[1] = (bf16)(xb[p].y - m4.y);
                zb[2] = (bf16)(xb[p].z - m4.z); zb[3] = (bf16)(xb[p].w - m4.w);
                *(bf16x4*)&bsh[row * RS + fseg * 4] = zb;
            }
        }
    };
    auto compute_it = [&]() {
        const bf16* bb = diag ? ash : bsh;
        bf16x8 af[4], bfv[4];
#pragma unroll
        for (int i = 0; i < 4; ++i)
            af[i] = *(const bf16x8*)&ash[(i * 16 + l15) * RS + quad * 8];
#pragma unroll
        for (int j = 0; j < 4; ++j)
            bfv[j] = *(const bf16x8*)&bb[(j * 16 + l15) * RS + quad * 8];
#pragma unroll
        for (int i = 0; i < 4; ++i)
#pragma unroll
            for (int j = 0; j < 4; ++j)
                acc[i][j] = __builtin_amdgcn_mfma_f32_16x16x32_bf16(
                    af[i], bfv[j], acc[i][j], 0, 0, 0);
    };

    load_it(0, xa0, xb0, me0, mo0);
    load_it(1, xa1, xb1, me1, mo1);
    for (int it = 0; it < NIT; it += 2) {
        stage_it(xa0, xb0, me0, mo0);                    // waits loads(it)
        if (it + 2 < NIT) load_it(it + 2, xa0, xb0, me0, mo0);
        compute_it();                                    // tile it
        stage_it(xa1, xb1, me1, mo1);                    // waits loads(it+1)
        if (it + 3 < NIT) load_it(it + 3, xa1, xb1, me1, mo1);
        compute_it();                                    // tile it+1
    }

    float* gp = Gp + (size_t)(ks * NTILE + tile) * 4096;
#pragma unroll
    for (int i = 0; i < 4; ++i) {
        int lr0 = i * 16 + quad * 4;
#pragma unroll
        for (int j = 0; j < 4; ++j) {
            int lc = j * 16 + l15;
#pragma unroll
            for (int r = 0; r < 4; ++r)
                gp[(lr0 + r) * 64 + lc] = acc[i][j][r];
        }
    }
}

// ---------------------------------------------------------------- kernel 2
// Reduce partials -> full symmetric G + per-row inverse norm. Zeroes out[0].
__global__ __launch_bounds__(256) void k_red(const float* __restrict__ Gp,
                                             float* __restrict__ G,
                                             float* __restrict__ invn,
                                             float* __restrict__ out) {
    int t = blockIdx.x * 256 + threadIdx.x;    // 336 blocks -> 86016 threads
    if (t == 0) out[0] = 0.0f;
    int tile = t >> 12;
    int idx  = t & 4095;
    int lr   = idx >> 6, lc = idx & 63;
    const float* p = Gp + (size_t)tile * 4096 + idx;
    float s = 0.0f;
#pragma unroll 8
    for (int ks = 0; ks < KSPLIT; ++ks) s += p[(size_t)ks * (NTILE * 4096)];
    int tp = 0, rem = tile;
    while (rem >= 6 - tp) { rem -= 6 - tp; ++tp; }
    int tq = tp + rem;
    int a = tp * 64 + lr, b = tq * 64 + lc;
    G[(size_t)a * NR + b] = s;
    G[(size_t)b * NR + a] = s;
    if (a == b) invn[a] = 1.0f / fmaxf(sqrtf(s), 1e-6f);
}

// ---------------------------------------------------------------- kernel 3
// One wave per row a: Ds[a] = sum_b mask*exp(S[a][b]); then lane 0 adds this
// row's 4 pair-slot terms  (-num + log(exp(num)+Ds[a]))  to out.
__global__ __launch_bounds__(256) void k_dsum(const float* __restrict__ G,
                                              const float* __restrict__ invn,
                                              float* __restrict__ out) {
    const int lane = threadIdx.x & 63;
    const int a    = blockIdx.x * 4 + (threadIdx.x >> 6);
    float ia  = invn[a];
    int arem  = a & 15;
    float acc = 0.0f;
    for (int b = lane; b < NR; b += 64) {
        float s = G[(size_t)a * NR + b] * ia * invn[b] * 10.0f;
        if ((b & 15) != arem) acc += expf(s);
    }
#pragma unroll
    for (int o = 32; o > 0; o >>= 1) acc += __shfl_down(acc, o);
    if (lane == 0) {
        float Dsa = acc;
        int pr[4];
        if (a < 16)       { pr[0] = 192 + a; pr[1] = a + 16;  pr[2] = a + 192; pr[3] = a + 368; }
        else if (a < 192) { pr[0] = 192 + a; pr[1] = a + 16;  pr[2] = a + 192; pr[3] = a - 16; }
        else if (a < 368) { pr[0] = a - 192; pr[1] = a + 16;  pr[2] = a - 192; pr[3] = a - 16; }
        else              { pr[0] = a - 192; pr[1] = a - 368; pr[2] = a - 192; pr[3] = a - 16; }
        float t = 0.0f;
#pragma unroll
        for (int s = 0; s < 4; ++s) {
            int b = pr[s];
            float num = G[(size_t)a * NR + b] * ia * invn[b] * 10.0f;
            t += -num + logf(expf(num) + Dsa);
        }
        atomicAdd(out, t * (1.0f / 576.0f));   // / (N_TRANSFORMS*3*BS)
    }
}

// ---------------------------------------------------------------- launch
extern "C" void kernel_launch(void* const* d_in, const int* in_sizes, int n_in,
                              void* d_out, int out_size, void* d_ws, size_t ws_size,
                              hipStream_t stream) {
    const float* X = (const float*)d_in[0];
    const float* M = (const float*)d_in[1];
    float* out = (float*)d_out;

    char* ws = (char*)d_ws;
    float* Gp   = (float*)ws;                                  // 33 MB
    float* G    = Gp + (size_t)KSPLIT * NTILE * 4096;          // 590 KB
    float* invn = G + (size_t)NR * NR;

    k_gram<<<dim3(8 * NTILE * (KSPLIT / 8)), dim3(64), 0, stream>>>(X, M, Gp);
    k_red<<<dim3(336), dim3(256), 0, stream>>>(Gp, G, invn, out);
    k_dsum<<<dim3(NR / 4), dim3(256), 0, stream>>>(G, invn, out);
}